// Round 8
// baseline (865.382 us; speedup 1.0000x reference)
//
#include <hip/hip_runtime.h>

#define T_STEPS 500
#define BATCH   2048
#define NIN     12
#define NL1     38
#define NL2     7

// fp32 I/O, FLOAT64 internal math — emulates a numpy float64 recompute of the
// scan exactly (inputs promoted f32->f64 exactly; all ops f64):
//   - cur1 = x . W1[row]: sequential f64 FMA ascending k (BLAS dgemm order)
//   - elementwise: ((beta1*mem1) + cur1) + (V*spk1), each f64 op rounded
//   - cur2: spikes in {0,1} -> masked sequential f64 add ascending j (exact)
//   - outputs cast f64 -> f32 on store (matches ref cast for comparison)
// One wave per batch element: lanes 0..37 = layer-1 neurons, 38..44 = layer-2.
__global__ __launch_bounds__(256) void snn_kernel(
    const float* __restrict__ x,  const float* __restrict__ W1,
    const float* __restrict__ V,  const float* __restrict__ W2,
    const float* __restrict__ b1p, const float* __restrict__ b2p,
    const float* __restrict__ thrp, float* __restrict__ out, int out_n)
{
#pragma clang fp contract(off)
    const int tid  = threadIdx.x;
    const int lane = tid & 63;
    const int wave = tid >> 6;
    const int b    = blockIdx.x * 4 + wave;

    const double beta1 = (double)b1p[0];
    const double beta2 = (double)b2p[0];
    const double thr   = (double)thrp[0];

    const bool isL1 = lane < NL1;
    const bool isL2 = (lane >= NL1) && (lane < NL1 + NL2);

    // layer-1 per-lane weights (f32 -> f64, exact)
    double w1r[NIN];
    #pragma unroll
    for (int i = 0; i < NIN; ++i)
        w1r[i] = isL1 ? (double)W1[lane * NIN + i] : 0.0;
    const double vj = isL1 ? (double)V[lane] : 0.0;

    // layer-2 per-lane weight row (k=0 fallback keeps address in-bounds)
    double w2r[NL1];
    {
        const int k = isL2 ? (lane - NL1) : 0;
        #pragma unroll
        for (int j = 0; j < NL1; ++j)
            w2r[j] = (double)W2[k * NL1 + j];
    }

    const int S1 = T_STEPS * BATCH * NL1;
    const int S2 = T_STEPS * BATCH * NL2;
    int off_spk = isL1 ? (b * NL1 + lane)      : (2 * S1 + b * NL2 + (lane - NL1));
    int off_mem = isL1 ? (S1 + b * NL1 + lane) : (2 * S1 + S2 + b * NL2 + (lane - NL1));
    const int stride = isL1 ? (BATCH * NL1) : (BATCH * NL2);
    const bool active = isL1 || isL2;

    const float* xb = x + (size_t)b * NIN;   // wave-uniform address

    double mem1 = 0.0, mem2 = 0.0, spk1 = 0.0;

    for (int t = 0; t < T_STEPS; ++t) {
        double xv[NIN];
        #pragma unroll
        for (int i = 0; i < NIN; ++i) xv[i] = (double)xb[i];
        xb += BATCH * NIN;

        // cur1: sequential f64 FMA ascending k (dgemm microkernel order)
        double cur1 = 0.0;
        #pragma unroll
        for (int i = 0; i < NIN; ++i) cur1 = __builtin_fma(xv[i], w1r[i], cur1);

        // mem1 = ((beta1*mem1) + cur1) + (V*spk1) — separately rounded f64
        mem1 = ((beta1 * mem1) + cur1) + (vj * spk1);
        const bool sp = (mem1 - thr) > 0.0;
        spk1 = sp ? 1.0 : 0.0;
        mem1 = mem1 - (spk1 * thr);

        const unsigned long long mask = __ballot(sp);

        // cur2: masked sequential f64 add ascending j (exact for {0,1} spikes)
        double cur2 = 0.0;
        #pragma unroll
        for (int j = 0; j < NL1; ++j) {
            const double sel = ((mask >> j) & 1ull) ? w2r[j] : 0.0;
            cur2 = cur2 + sel;
        }

        mem2 = (beta2 * mem2) + cur2;
        const double spk2 = ((mem2 - thr) > 0.0) ? 1.0 : 0.0;
        mem2 = mem2 - (spk2 * thr);

        if (active) {
            if (off_spk < out_n) out[off_spk] = (float)(isL1 ? spk1 : spk2);
            if (off_mem < out_n) out[off_mem] = (float)(isL1 ? mem1 : mem2);
        }
        off_spk += stride;
        off_mem += stride;
    }
}

extern "C" void kernel_launch(void* const* d_in, const int* in_sizes, int n_in,
                              void* d_out, int out_size, void* d_ws, size_t ws_size,
                              hipStream_t stream) {
    // Default: dict order (x, W1, V, W2, beta1, beta2, threshold).
    const void* x   = d_in[0];
    const void* W1p = (n_in > 1) ? d_in[1] : d_in[0];
    const void* Vp  = (n_in > 2) ? d_in[2] : d_in[0];
    const void* W2p = (n_in > 3) ? d_in[3] : d_in[0];
    const void* b1  = (n_in > 4) ? d_in[4] : d_in[0];
    const void* b2  = (n_in > 5) ? d_in[5] : d_in[0];
    const void* th  = (n_in > 6) ? d_in[6] : d_in[0];

    // Size-based override (element counts), only replaces on exact match.
    {
        const void* sc[3] = {0, 0, 0};
        int ns = 0;
        for (int i = 0; i < n_in; ++i) {
            const int s = in_sizes[i];
            if      (s == T_STEPS * BATCH * NIN) x   = d_in[i];
            else if (s == NL1 * NIN)             W1p = d_in[i];
            else if (s == NL2 * NL1)             W2p = d_in[i];
            else if (s == NL1)                   Vp  = d_in[i];
            else if (s == 1 && ns < 3)           sc[ns++] = d_in[i];
        }
        if (ns == 3) { b1 = sc[0]; b2 = sc[1]; th = sc[2]; }
    }

    snn_kernel<<<BATCH / 4, 256, 0, stream>>>(
        (const float*)x, (const float*)W1p, (const float*)Vp, (const float*)W2p,
        (const float*)b1, (const float*)b2, (const float*)th,
        (float*)d_out, out_size);
}